// Round 6
// baseline (573.659 us; speedup 1.0000x reference)
//
#include <hip/hip_runtime.h>
#include <cstdint>

#define D 128
#define H 4
#define N_ENT 100000
#define N_EDGE 400000
#define R 32

#define SCAN_NB ((N_ENT + 511) / 512)  // 196 blocks of 512 elements
#define CDIV(a, b) (((a) + (b) - 1) / (b))

// ---------------------------------------------------------------------------
// CSR build: histogram -> hierarchical scan -> scatter (permuted tail/etype).
// ---------------------------------------------------------------------------
__global__ void k_hist(const int* __restrict__ head, int* __restrict__ deg) {
  const int e = blockIdx.x * 256 + threadIdx.x;
  if (e < N_EDGE) atomicAdd(&deg[head[e]], 1);
}

__global__ __launch_bounds__(256) void k_scan1(const int* __restrict__ deg,
                                               int* __restrict__ bsum) {
  const int t = threadIdx.x;
  const int i = blockIdx.x * 512 + t * 2;
  int v0 = (i < N_ENT) ? deg[i] : 0;
  int v1 = (i + 1 < N_ENT) ? deg[i + 1] : 0;
  int s = v0 + v1;
#pragma unroll
  for (int k = 1; k < 64; k <<= 1) s += __shfl_xor(s, k);
  __shared__ int ws[4];
  if ((t & 63) == 0) ws[t >> 6] = s;
  __syncthreads();
  if (t == 0) bsum[blockIdx.x] = ws[0] + ws[1] + ws[2] + ws[3];
}

__global__ __launch_bounds__(256) void k_scan2(const int* __restrict__ bsum,
                                               int* __restrict__ bbase,
                                               int* __restrict__ off) {
  __shared__ int sh[256];
  const int t = threadIdx.x;
  const int v = (t < SCAN_NB) ? bsum[t] : 0;
  sh[t] = v;
  __syncthreads();
  for (int d = 1; d < 256; d <<= 1) {
    const int u = (t >= d) ? sh[t - d] : 0;
    __syncthreads();
    sh[t] += u;
    __syncthreads();
  }
  if (t < SCAN_NB) bbase[t] = sh[t] - v;
  if (t == SCAN_NB - 1) off[N_ENT] = sh[t];
}

__global__ __launch_bounds__(256) void k_scan3(const int* __restrict__ deg,
                                               const int* __restrict__ bbase,
                                               int* __restrict__ off,
                                               int* __restrict__ cur) {
  __shared__ int sh[256];
  const int t = threadIdx.x;
  const int i = blockIdx.x * 512 + t * 2;
  const int v0 = (i < N_ENT) ? deg[i] : 0;
  const int v1 = (i + 1 < N_ENT) ? deg[i + 1] : 0;
  const int s = v0 + v1;
  sh[t] = s;
  __syncthreads();
  for (int d = 1; d < 256; d <<= 1) {
    const int u = (t >= d) ? sh[t - d] : 0;
    __syncthreads();
    sh[t] += u;
    __syncthreads();
  }
  const int ex = sh[t] - s + bbase[blockIdx.x];
  if (i < N_ENT) {
    off[i] = ex;
    cur[i] = ex;
  }
  if (i + 1 < N_ENT) {
    off[i + 1] = ex + v0;
    cur[i + 1] = ex + v0;
  }
}

__global__ void k_scatter(const int* __restrict__ head,
                          const int* __restrict__ tail,
                          const int* __restrict__ etype, int* __restrict__ cur,
                          int* __restrict__ tailP, int* __restrict__ etypeP) {
  const int e = blockIdx.x * 256 + threadIdx.x;
  if (e >= N_EDGE) return;
  const int hd = head[e];
  const int pos = atomicAdd(&cur[hd], 1);
  tailP[pos] = tail[e];
  etypeP[pos] = etype[e] - 1;
}

// ---------------------------------------------------------------------------
// K1: Q = entity_emb @ qTrans   (Q in d_out; consumed chunk-wise by k_pproj,
// then overwritten chunk-wise by k_kg)
// ---------------------------------------------------------------------------
__global__ __launch_bounds__(512) void k_qproj(const float* __restrict__ ent,
                                               const float* __restrict__ qT,
                                               float* __restrict__ Q) {
  __shared__ float sT[D * D];
  __shared__ float rows[D * 128];
  const int t = threadIdx.x;
  const int n0 = blockIdx.x * 128;
#pragma unroll
  for (int s = 0; s < 8; ++s) {
    const int idx = (s * 512 + t) * 4;
    *(float4*)&sT[idx] = *(const float4*)&qT[idx];
  }
  {
    const int g = t & 3;
    const int n = t >> 2;
    const int node = n0 + n;
    if (node < N_ENT) {
      const float* src = ent + (size_t)node * D;
#pragma unroll
      for (int s = 0; s < 8; ++s) {
        const int i = s * 16 + g * 4;
        float4 v = *(const float4*)&src[i];
        rows[(i + 0) * 128 + n] = v.x;
        rows[(i + 1) * 128 + n] = v.y;
        rows[(i + 2) * 128 + n] = v.z;
        rows[(i + 3) * 128 + n] = v.w;
      }
    } else {
#pragma unroll
      for (int s = 0; s < 8; ++s) {
        const int i = s * 16 + g * 4;
        rows[(i + 0) * 128 + n] = 0.f;
        rows[(i + 1) * 128 + n] = 0.f;
        rows[(i + 2) * 128 + n] = 0.f;
        rows[(i + 3) * 128 + n] = 0.f;
      }
    }
  }
  __syncthreads();
  const int jj = t & 15;
  const int ee = t >> 4;
  float acc[4][8];
#pragma unroll
  for (int a = 0; a < 4; ++a)
#pragma unroll
    for (int b = 0; b < 8; ++b) acc[a][b] = 0.f;
#pragma unroll 4
  for (int i = 0; i < D; ++i) {
    float4 b0 = *(float4*)&sT[i * D + jj * 8];
    float4 b1 = *(float4*)&sT[i * D + jj * 8 + 4];
    float4 a0 = *(float4*)&rows[i * 128 + ee * 4];
    float bv[8] = {b0.x, b0.y, b0.z, b0.w, b1.x, b1.y, b1.z, b1.w};
    float av[4] = {a0.x, a0.y, a0.z, a0.w};
#pragma unroll
    for (int a = 0; a < 4; ++a)
#pragma unroll
      for (int b = 0; b < 8; ++b) acc[a][b] = fmaf(av[a], bv[b], acc[a][b]);
  }
#pragma unroll
  for (int a = 0; a < 4; ++a) {
    const int node = n0 + ee * 4 + a;
    if (node < N_ENT) {
      float4 o0 = {acc[a][0], acc[a][1], acc[a][2], acc[a][3]};
      float4 o1 = {acc[a][4], acc[a][5], acc[a][6], acc[a][7]};
      *(float4*)&Q[(size_t)node * D + jj * 8] = o0;
      *(float4*)&Q[(size_t)node * D + jj * 8 + 4] = o1;
    }
  }
}

// ---------------------------------------------------------------------------
// K2: P[n,h,i] = sum_j kT[i,32h+j] * Q[n,32h+j]  — tiled GEMM, K=32.
// Tile: 128 nodes x 128 i, grid (nodeTiles, H), 256 threads, 8x8 reg tile.
// (Round-5 lesson: this GEMM embedded in the fused kernel with an 8-node
// tile was 512 scalar ds_reads/thread = the 285 us bottleneck.)
// ---------------------------------------------------------------------------
__global__ __launch_bounds__(256) void k_pproj(const float* __restrict__ Q,
                                               const float* __restrict__ kT,
                                               float* __restrict__ pbuf,
                                               const int c0, const int cn) {
  __shared__ float sB[32 * 128];  // sB[j][i] = kT[i][32h+j]
  __shared__ float sA[32 * 128];  // sA[j][nn] = Q[c0+n0+nn][32h+j]
  const int t = threadIdx.x;
  const int h = blockIdx.y;
  const int n0 = blockIdx.x * 128;
  {
    const int i = t & 127;
    const int jh = t >> 7;  // 0..1
    const float* kr = kT + (size_t)i * D + h * 32 + jh * 16;
#pragma unroll
    for (int s = 0; s < 4; ++s) {
      float4 v = *(const float4*)&kr[s * 4];
      const int j = jh * 16 + s * 4;
      sB[(j + 0) * 128 + i] = v.x;
      sB[(j + 1) * 128 + i] = v.y;
      sB[(j + 2) * 128 + i] = v.z;
      sB[(j + 3) * 128 + i] = v.w;
    }
  }
  {
    const int nn = t & 127;
    const int jh = t >> 7;
    float4 v[4] = {{0, 0, 0, 0}, {0, 0, 0, 0}, {0, 0, 0, 0}, {0, 0, 0, 0}};
    if (n0 + nn < cn) {
      const float* qr = Q + (size_t)(c0 + n0 + nn) * D + h * 32 + jh * 16;
#pragma unroll
      for (int s = 0; s < 4; ++s) v[s] = *(const float4*)&qr[s * 4];
    }
#pragma unroll
    for (int s = 0; s < 4; ++s) {
      const int j = jh * 16 + s * 4;
      sA[(j + 0) * 128 + nn] = v[s].x;
      sA[(j + 1) * 128 + nn] = v[s].y;
      sA[(j + 2) * 128 + nn] = v[s].z;
      sA[(j + 3) * 128 + nn] = v[s].w;
    }
  }
  __syncthreads();
  const int ng = t & 15;  // nodes ng*8..+8
  const int ig = t >> 4;  // i cols ig*8..+8
  float acc[8][8];
#pragma unroll
  for (int a = 0; a < 8; ++a)
#pragma unroll
    for (int b = 0; b < 8; ++b) acc[a][b] = 0.f;
#pragma unroll 4
  for (int j = 0; j < 32; ++j) {
    float4 a0 = *(float4*)&sA[j * 128 + ng * 8];
    float4 a1 = *(float4*)&sA[j * 128 + ng * 8 + 4];
    float4 b0 = *(float4*)&sB[j * 128 + ig * 8];
    float4 b1 = *(float4*)&sB[j * 128 + ig * 8 + 4];
    float av[8] = {a0.x, a0.y, a0.z, a0.w, a1.x, a1.y, a1.z, a1.w};
    float bv[8] = {b0.x, b0.y, b0.z, b0.w, b1.x, b1.y, b1.z, b1.w};
#pragma unroll
    for (int a = 0; a < 8; ++a)
#pragma unroll
      for (int b = 0; b < 8; ++b) acc[a][b] = fmaf(av[a], bv[b], acc[a][b]);
  }
#pragma unroll
  for (int a = 0; a < 8; ++a) {
    const int ln = n0 + ng * 8 + a;
    if (ln < cn) {
      float4 o0 = {acc[a][0], acc[a][1], acc[a][2], acc[a][3]};
      float4 o1 = {acc[a][4], acc[a][5], acc[a][6], acc[a][7]};
      *(float4*)&pbuf[(size_t)ln * 512 + h * 128 + ig * 8] = o0;
      *(float4*)&pbuf[(size_t)ln * 512 + h * 128 + ig * 8 + 4] = o1;
    }
  }
}

// ---------------------------------------------------------------------------
// K3: pure edge loop. One 32-lane half-wave per node, 8 nodes per 256-block,
// zero LDS. Reads P row (4x b128), loops edges with a MERGED 4-head shuffle
// reduction (15 ops + 1 exp vs naive 40 ops + 4 exp), writes normalized agg
// in-place over the P row.
// ---------------------------------------------------------------------------
__global__ __launch_bounds__(256) void k_edge(
    const float* __restrict__ ent, const float* __restrict__ wrel,
    float* __restrict__ pbuf, const int* __restrict__ off,
    const int* __restrict__ tailP, const int* __restrict__ etypeP,
    const int c0, const int cn) {
  const int t = threadIdx.x;
  const int l32 = t & 31;
  const int ln = blockIdx.x * 8 + (t >> 5);
  if (ln >= cn) return;  // whole half-wave exits together (ln uniform)
  const int n = c0 + ln;
  float* prow = pbuf + (size_t)ln * 512 + l32 * 4;
  const float4 P0 = *(const float4*)&prow[0];
  const float4 P1 = *(const float4*)&prow[128];
  const float4 P2 = *(const float4*)&prow[256];
  const float4 P3 = *(const float4*)&prow[384];
  float4 a0 = {0, 0, 0, 0}, a1 = {0, 0, 0, 0};
  float4 a2 = {0, 0, 0, 0}, a3 = {0, 0, 0, 0};
  float s0 = 0.f, s1 = 0.f, s2 = 0.f, s3 = 0.f;
  const int eb = off[n];
  const int deg = off[n + 1] - eb;
  for (int idx = 0; idx < deg; ++idx) {
    const int e = eb + idx;
    const int tl = tailP[e];
    const int ty = etypeP[e];
    const float4 x = *(const float4*)&ent[(size_t)tl * D + l32 * 4];
    const float4 r = *(const float4*)&wrel[(size_t)ty * D + l32 * 4];
    const float4 nh = {x.x * r.x, x.y * r.y, x.z * r.z, x.w * r.w};
    float d0 = nh.x * P0.x + nh.y * P0.y + nh.z * P0.z + nh.w * P0.w;
    float d1 = nh.x * P1.x + nh.y * P1.y + nh.z * P1.z + nh.w * P1.w;
    float d2 = nh.x * P2.x + nh.y * P2.y + nh.z * P2.z + nh.w * P2.w;
    float d3 = nh.x * P3.x + nh.y * P3.y + nh.z * P3.z + nh.w * P3.w;
    // merged 4-value reduction: lane l&3==j ends with full 32-lane sum of d_j
    float a01 = (l32 & 1) ? d1 : d0;
    float b01 = (l32 & 1) ? d0 : d1;
    a01 += __shfl_xor(b01, 1);
    float a23 = (l32 & 1) ? d3 : d2;
    float b23 = (l32 & 1) ? d2 : d3;
    a23 += __shfl_xor(b23, 1);
    float A = (l32 & 2) ? a23 : a01;
    float B = (l32 & 2) ? a01 : a23;
    A += __shfl_xor(B, 2);
    A += __shfl_xor(A, 4);
    A += __shfl_xor(A, 8);
    A += __shfl_xor(A, 16);
    const float ew = expf(fminf(fmaxf(A, -10.f), 10.f));
    const float e0 = __shfl(ew, 0, 4);
    const float e1 = __shfl(ew, 1, 4);
    const float e2 = __shfl(ew, 2, 4);
    const float e3 = __shfl(ew, 3, 4);
    a0.x = fmaf(e0, nh.x, a0.x); a0.y = fmaf(e0, nh.y, a0.y);
    a0.z = fmaf(e0, nh.z, a0.z); a0.w = fmaf(e0, nh.w, a0.w);
    a1.x = fmaf(e1, nh.x, a1.x); a1.y = fmaf(e1, nh.y, a1.y);
    a1.z = fmaf(e1, nh.z, a1.z); a1.w = fmaf(e1, nh.w, a1.w);
    a2.x = fmaf(e2, nh.x, a2.x); a2.y = fmaf(e2, nh.y, a2.y);
    a2.z = fmaf(e2, nh.z, a2.z); a2.w = fmaf(e2, nh.w, a2.w);
    a3.x = fmaf(e3, nh.x, a3.x); a3.y = fmaf(e3, nh.y, a3.y);
    a3.z = fmaf(e3, nh.z, a3.z); a3.w = fmaf(e3, nh.w, a3.w);
    s0 += e0; s1 += e1; s2 += e2; s3 += e3;
  }
  const float i0 = 1.f / (s0 + 1e-8f);
  const float i1 = 1.f / (s1 + 1e-8f);
  const float i2 = 1.f / (s2 + 1e-8f);
  const float i3 = 1.f / (s3 + 1e-8f);
  float4 o0 = {a0.x * i0, a0.y * i0, a0.z * i0, a0.w * i0};
  float4 o1 = {a1.x * i1, a1.y * i1, a1.z * i1, a1.w * i1};
  float4 o2 = {a2.x * i2, a2.y * i2, a2.z * i2, a2.w * i2};
  float4 o3 = {a3.x * i3, a3.y * i3, a3.z * i3, a3.w * i3};
  *(float4*)&prow[0] = o0;
  *(float4*)&prow[128] = o1;
  *(float4*)&prow[256] = o2;
  *(float4*)&prow[384] = o3;
}

// ---------------------------------------------------------------------------
// K4: kg[n,32h+c] = sum_d agg[n,h,d] * vT[d,32h+c] — tiled GEMM, K=128
// (4 K-chunks of 32). Tile 256 nodes x 32 cols, 128 threads, 8x8 reg tile.
// Writes into d_out (overwriting this chunk's Q rows, already consumed).
// ---------------------------------------------------------------------------
__global__ __launch_bounds__(128) void k_kg(const float* __restrict__ agg,
                                            const float* __restrict__ vT,
                                            float* __restrict__ kg,
                                            const int c0, const int cn) {
  __shared__ float sA[32 * 256];  // [j][nn]
  __shared__ float sB[32 * 32];   // [j][c]
  const int t = threadIdx.x;
  const int h = blockIdx.y;
  const int n0 = blockIdx.x * 256;
  const int ng = t & 31;  // nodes ng*8..+8
  const int cg = t >> 5;  // cols cg*8..+8 (0..3)
  float acc[8][8];
#pragma unroll
  for (int a = 0; a < 8; ++a)
#pragma unroll
    for (int b = 0; b < 8; ++b) acc[a][b] = 0.f;
  for (int kc = 0; kc < 4; ++kc) {
    {
      const int jj = t >> 2;
      const int cq = (t & 3) * 8;
      const float* vr = vT + (size_t)(kc * 32 + jj) * D + h * 32 + cq;
      *(float4*)&sB[jj * 32 + cq] = *(const float4*)&vr[0];
      *(float4*)&sB[jj * 32 + cq + 4] = *(const float4*)&vr[4];
    }
#pragma unroll
    for (int u = 0; u < 2; ++u) {
      const int nn = t * 2 + u;
      float4 v[8] = {{0, 0, 0, 0}, {0, 0, 0, 0}, {0, 0, 0, 0}, {0, 0, 0, 0},
                     {0, 0, 0, 0}, {0, 0, 0, 0}, {0, 0, 0, 0}, {0, 0, 0, 0}};
      if (n0 + nn < cn) {
        const float* ar = agg + (size_t)(n0 + nn) * 512 + h * 128 + kc * 32;
#pragma unroll
        for (int s = 0; s < 8; ++s) v[s] = *(const float4*)&ar[s * 4];
      }
#pragma unroll
      for (int s = 0; s < 8; ++s) {
        const int j = s * 4;
        sA[(j + 0) * 256 + nn] = v[s].x;
        sA[(j + 1) * 256 + nn] = v[s].y;
        sA[(j + 2) * 256 + nn] = v[s].z;
        sA[(j + 3) * 256 + nn] = v[s].w;
      }
    }
    __syncthreads();
#pragma unroll 4
    for (int j = 0; j < 32; ++j) {
      float4 a0 = *(float4*)&sA[j * 256 + ng * 8];
      float4 a1 = *(float4*)&sA[j * 256 + ng * 8 + 4];
      float4 b0 = *(float4*)&sB[j * 32 + cg * 8];
      float4 b1 = *(float4*)&sB[j * 32 + cg * 8 + 4];
      float av[8] = {a0.x, a0.y, a0.z, a0.w, a1.x, a1.y, a1.z, a1.w};
      float bv[8] = {b0.x, b0.y, b0.z, b0.w, b1.x, b1.y, b1.z, b1.w};
#pragma unroll
      for (int a = 0; a < 8; ++a)
#pragma unroll
        for (int b = 0; b < 8; ++b) acc[a][b] = fmaf(av[a], bv[b], acc[a][b]);
    }
    __syncthreads();
  }
#pragma unroll
  for (int a = 0; a < 8; ++a) {
    const int ln = n0 + ng * 8 + a;
    if (ln < cn) {
      float4 o0 = {acc[a][0], acc[a][1], acc[a][2], acc[a][3]};
      float4 o1 = {acc[a][4], acc[a][5], acc[a][6], acc[a][7]};
      *(float4*)&kg[(size_t)(c0 + ln) * D + h * 32 + cg * 8] = o0;
      *(float4*)&kg[(size_t)(c0 + ln) * D + h * 32 + cg * 8 + 4] = o1;
    }
  }
}

// ---------------------------------------------------------------------------
// K5: S[n,r] = sum_d kg[n,d]^2 * wrel[r,d]^2  (w(e) = S[head,ty]*S[tail,ty])
// ---------------------------------------------------------------------------
__global__ __launch_bounds__(256) void k_S(const float* __restrict__ kg,
                                           const float* __restrict__ wrel,
                                           float* __restrict__ S) {
  __shared__ float sB[D * 32];
  __shared__ float sA[D * 64];
  const int t = threadIdx.x;
  const int n0 = blockIdx.x * 64;
  {
    const int r = t & 31;
    const int qg = t >> 5;
#pragma unroll
    for (int s = 0; s < 4; ++s) {
      const int d = qg * 16 + s * 4;
      float4 b = *(const float4*)&wrel[(size_t)r * D + d];
      sB[(d + 0) * 32 + r] = b.x * b.x;
      sB[(d + 1) * 32 + r] = b.y * b.y;
      sB[(d + 2) * 32 + r] = b.z * b.z;
      sB[(d + 3) * 32 + r] = b.w * b.w;
    }
  }
  {
    const int nn = t & 63;
    const int dg = t >> 6;
    const int node = n0 + nn;
#pragma unroll
    for (int s = 0; s < 8; ++s) {
      const int d = dg * 32 + s * 4;
      float4 a = {0, 0, 0, 0};
      if (node < N_ENT) a = *(const float4*)&kg[(size_t)node * D + d];
      sA[(d + 0) * 64 + nn] = a.x * a.x;
      sA[(d + 1) * 64 + nn] = a.y * a.y;
      sA[(d + 2) * 64 + nn] = a.z * a.z;
      sA[(d + 3) * 64 + nn] = a.w * a.w;
    }
  }
  __syncthreads();
  const int nn2 = t >> 2;
  const int rg = t & 3;
  float acc[8];
#pragma unroll
  for (int c = 0; c < 8; ++c) acc[c] = 0.f;
#pragma unroll 4
  for (int d = 0; d < D; ++d) {
    const float a = sA[d * 64 + nn2];
    float4 b0 = *(float4*)&sB[d * 32 + rg * 8];
    float4 b1 = *(float4*)&sB[d * 32 + rg * 8 + 4];
    acc[0] = fmaf(a, b0.x, acc[0]);
    acc[1] = fmaf(a, b0.y, acc[1]);
    acc[2] = fmaf(a, b0.z, acc[2]);
    acc[3] = fmaf(a, b0.w, acc[3]);
    acc[4] = fmaf(a, b1.x, acc[4]);
    acc[5] = fmaf(a, b1.y, acc[5]);
    acc[6] = fmaf(a, b1.z, acc[6]);
    acc[7] = fmaf(a, b1.w, acc[7]);
  }
  const int node = n0 + nn2;
  if (node < N_ENT) {
    float4 o0 = {acc[0], acc[1], acc[2], acc[3]};
    float4 o1 = {acc[4], acc[5], acc[6], acc[7]};
    *(float4*)&S[(size_t)node * 32 + rg * 8] = o0;
    *(float4*)&S[(size_t)node * 32 + rg * 8 + 4] = o1;
  }
}

// ---------------------------------------------------------------------------
// K6: per-node online softmax over w(e)=S[n,ty]*S[tail,ty] + weighted gather.
// ---------------------------------------------------------------------------
__global__ __launch_bounds__(256) void k_out2(
    const float* __restrict__ ent, const float* __restrict__ S,
    const int* __restrict__ off, const int* __restrict__ tailP,
    const int* __restrict__ etypeP, float* __restrict__ out) {
  const int t = threadIdx.x;
  const int wid = t >> 6;
  const int lane = t & 63;
  const int n = blockIdx.x * 4 + wid;
  if (n >= N_ENT) return;
  const int eb = off[n];
  const int deg = off[n + 1] - eb;
  float accx = 0.f, accy = 0.f;
  float m = 0.f, ssum = 0.f;
  for (int b = 0; b < deg; b += 64) {
    const int idx = b + lane;
    const bool val = idx < deg;
    const int e = eb + (val ? idx : 0);
    const int tl = tailP[e];
    const int ty = etypeP[e];
    float w = val ? S[(size_t)n * 32 + ty] * S[(size_t)tl * 32 + ty] : -1.f;
    float cm = w;
#pragma unroll
    for (int k = 1; k < 64; k <<= 1) cm = fmaxf(cm, __shfl_xor(cm, k));
    const float mnew = fmaxf(m, cm);
    const float scale = expf(m - mnew);
    const float el = val ? expf(w - mnew) : 0.f;
    float cs = el;
#pragma unroll
    for (int k = 1; k < 64; k <<= 1) cs += __shfl_xor(cs, k);
    ssum = ssum * scale + cs;
    accx *= scale;
    accy *= scale;
    const int cnt = (deg - b < 64) ? deg - b : 64;
    for (int j = 0; j < cnt; ++j) {
      const float sj = __shfl(el, j);
      const int tlj = __shfl(tl, j);
      const float2 x = *(const float2*)&ent[(size_t)tlj * D + lane * 2];
      accx = fmaf(sj, x.x, accx);
      accy = fmaf(sj, x.y, accy);
    }
    m = mnew;
  }
  const float inv = (deg > 0) ? 1.f / ssum : 0.f;
  float2 o = {accx * inv, accy * inv};
  *(float2*)&out[(size_t)n * D + lane * 2] = o;
}

// ---------------------------------------------------------------------------
// Workspace: fixed region (S 12.8 MB + CSR ints 4.4 MB), then pbuf fills the
// REST of ws. Chunk size is derived from ws_size at runtime (node rows of
// 512 floats), so we can never exceed the workspace (round-2 lesson).
// d_out timeline: Q (k_qproj) -> per chunk: pproj reads Q rows, kg overwrites
// the same rows -> k_out2 writes the final output.
// ---------------------------------------------------------------------------
extern "C" void kernel_launch(void* const* d_in, const int* in_sizes, int n_in,
                              void* d_out, int out_size, void* d_ws,
                              size_t ws_size, hipStream_t stream) {
  const float* ent = (const float*)d_in[0];
  const float* wrel = (const float*)d_in[3];
  const float* qT = (const float*)d_in[4];
  const float* kT = (const float*)d_in[5];
  const float* vT = (const float*)d_in[6];
  const int* eidx = (const int*)d_in[7];
  const int* etype = (const int*)d_in[8];
  const int* head = eidx;
  const int* tail = eidx + N_EDGE;

  float* S = (float*)d_ws;
  int* off = (int*)(S + (size_t)N_ENT * 32);
  int* cur = off + (N_ENT + 1);
  int* deg = cur + N_ENT;
  int* bsum = deg + N_ENT;
  int* bbase = bsum + SCAN_NB;
  int* tailP = bbase + SCAN_NB;
  int* etypeP = tailP + N_EDGE;
  size_t fixedBytes = (size_t)((char*)(etypeP + N_EDGE) - (char*)d_ws);
  fixedBytes = (fixedBytes + 255) & ~(size_t)255;
  float* pbuf = (float*)((char*)d_ws + fixedBytes);
  size_t avail = (ws_size > fixedBytes) ? ws_size - fixedBytes : 0;
  long long cap = (long long)(avail / (512 * sizeof(float)));
  if (cap > N_ENT) cap = N_ENT;
  cap &= ~7LL;
  if (cap < 8) cap = 8;
  float* qkg = (float*)d_out;

  hipMemsetAsync(deg, 0, N_ENT * sizeof(int), stream);
  k_hist<<<(N_EDGE + 255) / 256, 256, 0, stream>>>(head, deg);
  k_scan1<<<SCAN_NB, 256, 0, stream>>>(deg, bsum);
  k_scan2<<<1, 256, 0, stream>>>(bsum, bbase, off);
  k_scan3<<<SCAN_NB, 256, 0, stream>>>(deg, bbase, off, cur);
  k_scatter<<<(N_EDGE + 255) / 256, 256, 0, stream>>>(head, tail, etype, cur,
                                                      tailP, etypeP);
  k_qproj<<<(N_ENT + 127) / 128, 512, 0, stream>>>(ent, qT, qkg);
  for (int c0 = 0; c0 < N_ENT; c0 += (int)cap) {
    const int cn = (N_ENT - c0 < (int)cap) ? (N_ENT - c0) : (int)cap;
    dim3 gp(CDIV(cn, 128), H);
    k_pproj<<<gp, 256, 0, stream>>>(qkg, kT, pbuf, c0, cn);
    k_edge<<<CDIV(cn, 8), 256, 0, stream>>>(ent, wrel, pbuf, off, tailP,
                                            etypeP, c0, cn);
    dim3 gk(CDIV(cn, 256), H);
    k_kg<<<gk, 128, 0, stream>>>(pbuf, vT, qkg, c0, cn);
  }
  k_S<<<(N_ENT + 63) / 64, 256, 0, stream>>>(qkg, wrel, S);
  k_out2<<<(N_ENT + 3) / 4, 256, 0, stream>>>(ent, S, off, tailP, etypeP,
                                              qkg);
}